// Round 8
// baseline (1024.154 us; speedup 1.0000x reference)
//
#include <hip/hip_runtime.h>

#define NN  40000
#define NE  640000
#define ND  128
#define ED  64
#define NH  8
#define DK  16
#define ED_S 68   // padded LDS stride per edge row (floats): kills write bank conflicts

#define SCAN_NBLK 157   // ceil(40000/256)

// ---------------- fused Q/K/V projection: 16 rows/block ----------------
__global__ __launch_bounds__(256) void proj_qkv(const float* __restrict__ x,
                                                const float* __restrict__ wq,
                                                const float* __restrict__ bq,
                                                const float* __restrict__ wk,
                                                const float* __restrict__ bk,
                                                const float* __restrict__ wv,
                                                const float* __restrict__ bv,
                                                float* __restrict__ Q,
                                                float* __restrict__ K,
                                                float* __restrict__ V) {
  __shared__ float xs[ND][20];
  const int r0 = blockIdx.x * 16;
  const int tid = threadIdx.x;
  for (int i = tid; i < 16 * ND; i += 256) {
    int r = i >> 7, c = i & 127;
    xs[c][r] = x[(size_t)(r0 + r) * ND + c];
  }
  __syncthreads();

  const int o = tid & 127;
  const int half = tid >> 7;
  float aq[8], ak[8], av[8];
#pragma unroll
  for (int j = 0; j < 8; ++j) { aq[j] = 0.f; ak[j] = 0.f; av[j] = 0.f; }

#pragma unroll 4
  for (int k = 0; k < ND; ++k) {
    float4 xa = *(const float4*)&xs[k][half * 8];
    float4 xb = *(const float4*)&xs[k][half * 8 + 4];
    float wqv = wq[k * ND + o];
    float wkv = wk[k * ND + o];
    float wvv = wv[k * ND + o];
    aq[0] = fmaf(xa.x, wqv, aq[0]); aq[1] = fmaf(xa.y, wqv, aq[1]);
    aq[2] = fmaf(xa.z, wqv, aq[2]); aq[3] = fmaf(xa.w, wqv, aq[3]);
    aq[4] = fmaf(xb.x, wqv, aq[4]); aq[5] = fmaf(xb.y, wqv, aq[5]);
    aq[6] = fmaf(xb.z, wqv, aq[6]); aq[7] = fmaf(xb.w, wqv, aq[7]);
    ak[0] = fmaf(xa.x, wkv, ak[0]); ak[1] = fmaf(xa.y, wkv, ak[1]);
    ak[2] = fmaf(xa.z, wkv, ak[2]); ak[3] = fmaf(xa.w, wkv, ak[3]);
    ak[4] = fmaf(xb.x, wkv, ak[4]); ak[5] = fmaf(xb.y, wkv, ak[5]);
    ak[6] = fmaf(xb.z, wkv, ak[6]); ak[7] = fmaf(xb.w, wkv, ak[7]);
    av[0] = fmaf(xa.x, wvv, av[0]); av[1] = fmaf(xa.y, wvv, av[1]);
    av[2] = fmaf(xa.z, wvv, av[2]); av[3] = fmaf(xa.w, wvv, av[3]);
    av[4] = fmaf(xb.x, wvv, av[4]); av[5] = fmaf(xb.y, wvv, av[5]);
    av[6] = fmaf(xb.z, wvv, av[6]); av[7] = fmaf(xb.w, wvv, av[7]);
  }
  const float bqv = bq[o], bkv = bk[o], bvv = bv[o];
  const size_t base = (size_t)(r0 + half * 8) * ND + o;
#pragma unroll
  for (int j = 0; j < 8; ++j) {
    Q[base + (size_t)j * ND] = aq[j] + bqv;
    K[base + (size_t)j * ND] = ak[j] + bkv;
    V[base + (size_t)j * ND] = av[j] + bvv;
  }
}

// ---------------- out = msgn @ W + b: 16 rows/block ----------------
__global__ __launch_bounds__(256) void proj128(const float* __restrict__ x,
                                               const float* __restrict__ W,
                                               const float* __restrict__ b,
                                               float* __restrict__ y) {
  __shared__ float xs[ND][20];
  const int r0 = blockIdx.x * 16;
  const int tid = threadIdx.x;
  for (int i = tid; i < 16 * ND; i += 256) {
    int r = i >> 7, c = i & 127;
    xs[c][r] = x[(size_t)(r0 + r) * ND + c];
  }
  __syncthreads();
  const int o = tid & 127;
  const int half = tid >> 7;
  float a[8];
#pragma unroll
  for (int j = 0; j < 8; ++j) a[j] = 0.f;
#pragma unroll 8
  for (int k = 0; k < ND; ++k) {
    float4 xa = *(const float4*)&xs[k][half * 8];
    float4 xb = *(const float4*)&xs[k][half * 8 + 4];
    float w = W[k * ND + o];
    a[0] = fmaf(xa.x, w, a[0]); a[1] = fmaf(xa.y, w, a[1]);
    a[2] = fmaf(xa.z, w, a[2]); a[3] = fmaf(xa.w, w, a[3]);
    a[4] = fmaf(xb.x, w, a[4]); a[5] = fmaf(xb.y, w, a[5]);
    a[6] = fmaf(xb.z, w, a[6]); a[7] = fmaf(xb.w, w, a[7]);
  }
  const float bb = b[o];
  const size_t base = (size_t)(r0 + half * 8) * ND + o;
#pragma unroll
  for (int j = 0; j < 8; ++j) y[base + (size_t)j * ND] = a[j] + bb;
}

// ---------------- CSR build ----------------
__global__ __launch_bounds__(256) void k_hist(const int* __restrict__ ei,
                                              int* __restrict__ hist) {
  int e = blockIdx.x * 256 + threadIdx.x;
  if (e < NE) atomicAdd(&hist[ei[e]], 1);
}

__global__ __launch_bounds__(256) void k_scan1(const int* __restrict__ hist,
                                               int* __restrict__ off,
                                               int* __restrict__ bsum) {
  __shared__ int sh[256];
  const int tid = threadIdx.x;
  const int idx = blockIdx.x * 256 + tid;
  int v = (idx < NN) ? hist[idx] : 0;
  sh[tid] = v;
  __syncthreads();
#pragma unroll
  for (int d = 1; d < 256; d <<= 1) {
    int t = (tid >= d) ? sh[tid - d] : 0;
    __syncthreads();
    sh[tid] += t;
    __syncthreads();
  }
  if (idx < NN) off[idx] = sh[tid] - v;
  if (tid == 255) bsum[blockIdx.x] = sh[255];
}

__global__ __launch_bounds__(256) void k_scan2(int* __restrict__ bsum) {
  __shared__ int sh[256];
  const int tid = threadIdx.x;
  int v = (tid < SCAN_NBLK) ? bsum[tid] : 0;
  sh[tid] = v;
  __syncthreads();
#pragma unroll
  for (int d = 1; d < 256; d <<= 1) {
    int t = (tid >= d) ? sh[tid - d] : 0;
    __syncthreads();
    sh[tid] += t;
    __syncthreads();
  }
  if (tid < SCAN_NBLK) bsum[tid] = sh[tid] - v;
}

__global__ __launch_bounds__(256) void k_scan3(int* __restrict__ off,
                                               const int* __restrict__ bsum,
                                               int* __restrict__ cursor) {
  const int idx = blockIdx.x * 256 + threadIdx.x;
  if (idx < NN) {
    int o = off[idx] + bsum[blockIdx.x];
    off[idx] = o;
    cursor[idx] = o;
  }
  if (blockIdx.x == 0 && threadIdx.x == 0) off[NN] = NE;
}

__global__ __launch_bounds__(256) void k_scatter(const int* __restrict__ ei,
                                                 int* __restrict__ cursor,
                                                 int2* __restrict__ pair) {
  int e = blockIdx.x * 256 + threadIdx.x;
  if (e >= NE) return;
  int row = ei[e];
  int col = ei[NE + e];
  int pos = atomicAdd(&cursor[row], 1);
  pair[pos] = make_int2(col, e);
}

// ---------------- fused gather: 1 node / 64-lane wave, ping-pong reg pipeline ----
// lane l = (e2<<5)|(h<<2)|q. Chunk = 16 edges (8 per e2-half). All chunk-(t+1)
// loads (K/V + cols(t+2) + eid(t+2)) issue BEFORE chunk-t compute; ping-pong
// register sets kz/vz[A|B] (static indices) keep them in flight. Prefetch is
// skipped on the last chunk (wave-uniform branch). All indices clamped to the
// node's last edge -> dup L1 hits, no wasted fetch.
#define GBODY(CUR, NXT, T) do {                                                \
  const int jp = j0 + (T) * 16;                                                \
  const int ebase = jp + e2 * 8;                                               \
  if ((T) + 1 < nch) {                                                         \
    _Pragma("unroll")                                                          \
    for (int i = 0; i < 8; ++i) {                                              \
      kz##NXT[i] = *(const float4*)(K + (size_t)cz##NXT[i] * ND + hq);         \
      vz##NXT[i] = *(const float4*)(V + (size_t)cz##NXT[i] * ND + hq);         \
    }                                                                          \
    eidN = pair[min(jp + 32 + me, jlast)].y;                                   \
    _Pragma("unroll")                                                          \
    for (int x = 0; x < 8; ++x)                                                \
      cz##CUR[x] = pair[min(jp + 32 + e2 * 8 + x, jlast)].x;                   \
  }                                                                            \
  __builtin_amdgcn_sched_barrier(0);                                           \
  asm volatile("s_waitcnt lgkmcnt(0)" ::: "memory");                           \
  __builtin_amdgcn_sched_barrier(0);                                           \
  _Pragma("unroll")                                                            \
  for (int c = 0; c < 8; ++c) {                                                \
    float4 kv = kz##CUR[c];                                                    \
    float s = fmaf(qv.w, kv.w, fmaf(qv.z, kv.z, fmaf(qv.y, kv.y, kv.x * qv.x)));\
    const float* ep = myl + (e2 * 8 + c) * ED_S + q * 16;                      \
    float4 a;                                                                  \
    a = *(const float4*)(ep + 0);                                              \
    s = fmaf(a.x, gg[0], s);  s = fmaf(a.y, gg[1], s);                         \
    s = fmaf(a.z, gg[2], s);  s = fmaf(a.w, gg[3], s);                         \
    a = *(const float4*)(ep + 4);                                              \
    s = fmaf(a.x, gg[4], s);  s = fmaf(a.y, gg[5], s);                         \
    s = fmaf(a.z, gg[6], s);  s = fmaf(a.w, gg[7], s);                         \
    a = *(const float4*)(ep + 8);                                              \
    s = fmaf(a.x, gg[8], s);  s = fmaf(a.y, gg[9], s);                         \
    s = fmaf(a.z, gg[10], s); s = fmaf(a.w, gg[11], s);                        \
    a = *(const float4*)(ep + 12);                                             \
    s = fmaf(a.x, gg[12], s); s = fmaf(a.y, gg[13], s);                        \
    s = fmaf(a.z, gg[14], s); s = fmaf(a.w, gg[15], s);                        \
    s += __shfl_xor(s, 1); s += __shfl_xor(s, 2);                              \
    float es = (ebase + c < j1) ? __expf(fmaf(s, 0.25f, sb)) : 0.f;            \
    den += es;                                                                 \
    float4 vv = vz##CUR[c];                                                    \
    acc.x = fmaf(es, vv.x, acc.x); acc.y = fmaf(es, vv.y, acc.y);              \
    acc.z = fmaf(es, vv.z, acc.z); acc.w = fmaf(es, vv.w, acc.w);              \
  }                                                                            \
  if ((T) + 1 < nch) {                                                         \
    float* d = myl + me * ED_S + mp * 4;                                       \
    *(float4*)(d + 0)  = er0; *(float4*)(d + 16) = er1;                        \
    *(float4*)(d + 32) = er2; *(float4*)(d + 48) = er3;                        \
    const float4* s4 = (const float4*)(ea + (size_t)eidN * ED) + mp;           \
    er0 = s4[0]; er1 = s4[4]; er2 = s4[8]; er3 = s4[12];                       \
  }                                                                            \
} while (0)

__global__ __launch_bounds__(256, 2) void k_gather(const float* __restrict__ Q,
                                                   const float* __restrict__ K,
                                                   const float* __restrict__ V,
                                                   const float* __restrict__ we,
                                                   const float* __restrict__ be,
                                                   const float* __restrict__ ea,
                                                   const int* __restrict__ off,
                                                   const int2* __restrict__ pair,
                                                   float* __restrict__ msgn) {
  __shared__ float eas[4][16 * ED_S];   // 4 waves x 16 edges x 68 floats = 17 KB
  const int wid = threadIdx.x >> 6;
  const int n = blockIdx.x * 4 + wid;
  const int l = threadIdx.x & 63;
  const int e2 = l >> 5;
  const int h = (l >> 2) & 7;
  const int q = l & 3;
  const int me = l >> 2;   // staging edge 0..15
  const int mp = l & 3;    // staging float4-part

  // ---- per-node setup: Q frag, sb, gg ----
  float qf[DK];
  {
    const float4* qp = (const float4*)(Q + (size_t)n * ND + h * DK);
#pragma unroll
    for (int i = 0; i < 4; ++i) {
      float4 v = qp[i];
      qf[4 * i + 0] = v.x; qf[4 * i + 1] = v.y;
      qf[4 * i + 2] = v.z; qf[4 * i + 3] = v.w;
    }
  }
  float sbase = 0.f;
  {
    const float4* bp = (const float4*)(be + h * DK);
#pragma unroll
    for (int i = 0; i < 4; ++i) {
      float4 b = bp[i];
      sbase = fmaf(qf[4 * i + 0], b.x, sbase);
      sbase = fmaf(qf[4 * i + 1], b.y, sbase);
      sbase = fmaf(qf[4 * i + 2], b.z, sbase);
      sbase = fmaf(qf[4 * i + 3], b.w, sbase);
    }
  }
  const float sb = sbase * 0.25f;

  float gg[16];
#pragma unroll
  for (int jj = 0; jj < 16; ++jj) {
    const float4* wp = (const float4*)(we + (size_t)(q * 16 + jj) * ND + h * DK);
    float s = 0.f;
#pragma unroll
    for (int i = 0; i < 4; ++i) {
      float4 w = wp[i];
      s = fmaf(qf[4 * i + 0], w.x, s);
      s = fmaf(qf[4 * i + 1], w.y, s);
      s = fmaf(qf[4 * i + 2], w.z, s);
      s = fmaf(qf[4 * i + 3], w.w, s);
    }
    gg[jj] = s;
  }

  float4 qv;
  qv.x = qf[q * 4 + 0]; qv.y = qf[q * 4 + 1];
  qv.z = qf[q * 4 + 2]; qv.w = qf[q * 4 + 3];

  const int j0 = off[n], j1 = off[n + 1];
  const int nch = (j1 - j0 + 15) >> 4;
  const int jlast = j1 - 1;
  const int hq = h * DK + q * 4;

  float4 acc = make_float4(0.f, 0.f, 0.f, 0.f);
  float den = 0.f;

  if (nch > 0) {
    float* myl = &eas[wid][0];
    float4 kzA[8], vzA[8], kzB[8], vzB[8];
    int czA[8], czB[8];
    float4 er0, er1, er2, er3;
    int eidN;

    // ---- prologue ----
    {  // stage ea(chunk 0) -> LDS
      const int eid = pair[min(j0 + me, jlast)].y;
      const float4* s = (const float4*)(ea + (size_t)eid * ED) + mp;
      float4 a0 = s[0], a1 = s[4], a2 = s[8], a3 = s[12];
      float* d = myl + me * ED_S + mp * 4;
      *(float4*)(d + 0)  = a0; *(float4*)(d + 16) = a1;
      *(float4*)(d + 32) = a2; *(float4*)(d + 48) = a3;
    }
#pragma unroll
    for (int x = 0; x < 8; ++x) czA[x] = pair[min(j0 + e2 * 8 + x, jlast)].x;
#pragma unroll
    for (int i = 0; i < 8; ++i) {   // chunk-0 K/V
      kzA[i] = *(const float4*)(K + (size_t)czA[i] * ND + hq);
      vzA[i] = *(const float4*)(V + (size_t)czA[i] * ND + hq);
    }
    if (nch > 1) {   // wave-uniform
#pragma unroll
      for (int x = 0; x < 8; ++x) czB[x] = pair[min(j0 + 16 + e2 * 8 + x, jlast)].x;
      const int eid = pair[min(j0 + 16 + me, jlast)].y;
      const float4* s = (const float4*)(ea + (size_t)eid * ED) + mp;
      er0 = s[0]; er1 = s[4]; er2 = s[8]; er3 = s[12];
    }

    for (int t = 0; t < nch; t += 2) {
      GBODY(A, B, t);
      if (t + 1 < nch) GBODY(B, A, t + 1);
    }
  }

  // merge the two 32-lane halves
  den += __shfl_xor(den, 32);
  acc.x += __shfl_xor(acc.x, 32);
  acc.y += __shfl_xor(acc.y, 32);
  acc.z += __shfl_xor(acc.z, 32);
  acc.w += __shfl_xor(acc.w, 32);

  if (l < 32) {
    const float inv = 1.f / (den + 1e-8f);
    float4 o;
    o.x = acc.x * inv; o.y = acc.y * inv; o.z = acc.z * inv; o.w = acc.w * inv;
    *(float4*)(msgn + (size_t)n * ND + h * DK + q * 4) = o;
  }
}

extern "C" void kernel_launch(void* const* d_in, const int* in_sizes, int n_in,
                              void* d_out, int out_size, void* d_ws, size_t ws_size,
                              hipStream_t stream) {
  const float* nodes = (const float*)d_in[0];
  const int*   ei    = (const int*)d_in[1];
  const float* ea    = (const float*)d_in[2];
  const float* wq    = (const float*)d_in[3];
  const float* bq    = (const float*)d_in[4];
  const float* wk    = (const float*)d_in[5];
  const float* bk    = (const float*)d_in[6];
  const float* wv    = (const float*)d_in[7];
  const float* bv    = (const float*)d_in[8];
  const float* we    = (const float*)d_in[9];
  const float* be    = (const float*)d_in[10];
  const float* wo    = (const float*)d_in[11];
  const float* bo    = (const float*)d_in[12];
  float* out = (float*)d_out;

  float* ws = (float*)d_ws;
  const size_t NND = (size_t)NN * ND;
  float* Q    = ws;
  float* K    = Q + NND;
  float* V    = K + NND;
  float* msgn = V + NND;
  int* hist   = (int*)(msgn + NND);
  int* off    = hist + NN;            // NN+1 (padded to 40004)
  int* cursor = off + 40004;
  int* bsum   = cursor + NN;
  int2* pair  = (int2*)(bsum + 256);  // NE int2

  hipMemsetAsync(hist, 0, NN * sizeof(int), stream);

  dim3 blk(256);

  proj_qkv<<<dim3(NN / 16), blk, 0, stream>>>(nodes, wq, bq, wk, bk, wv, bv, Q, K, V);

  dim3 gE((NE + 255) / 256);
  k_hist<<<gE, blk, 0, stream>>>(ei, hist);
  k_scan1<<<dim3(SCAN_NBLK), blk, 0, stream>>>(hist, off, bsum);
  k_scan2<<<dim3(1), blk, 0, stream>>>(bsum);
  k_scan3<<<dim3(SCAN_NBLK), blk, 0, stream>>>(off, bsum, cursor);
  k_scatter<<<gE, blk, 0, stream>>>(ei, cursor, pair);

  k_gather<<<dim3(NN / 4), blk, 0, stream>>>(Q, K, V, we, be, ea, off, pair, msgn);

  proj128<<<dim3(NN / 16), blk, 0, stream>>>(msgn, wo, bo, out);
}

// Round 9
// 311.585 us; speedup vs baseline: 3.2869x; 3.2869x over previous
//
#include <hip/hip_runtime.h>
#include <hip/hip_fp16.h>

#define NN  40000
#define NE  640000
#define ND  128
#define ED  64
#define NH  8
#define DK  16

#define SCAN_NBLK 157   // ceil(40000/256)

// ---------------- fused Q/K/V projection: 16 rows/block ----------------
__global__ __launch_bounds__(256) void proj_qkv(const float* __restrict__ x,
                                                const float* __restrict__ wq,
                                                const float* __restrict__ bq,
                                                const float* __restrict__ wk,
                                                const float* __restrict__ bk,
                                                const float* __restrict__ wv,
                                                const float* __restrict__ bv,
                                                float* __restrict__ Q,
                                                float* __restrict__ K,
                                                float* __restrict__ V) {
  __shared__ float xs[ND][20];
  const int r0 = blockIdx.x * 16;
  const int tid = threadIdx.x;
  for (int i = tid; i < 16 * ND; i += 256) {
    int r = i >> 7, c = i & 127;
    xs[c][r] = x[(size_t)(r0 + r) * ND + c];
  }
  __syncthreads();

  const int o = tid & 127;
  const int half = tid >> 7;
  float aq[8], ak[8], av[8];
#pragma unroll
  for (int j = 0; j < 8; ++j) { aq[j] = 0.f; ak[j] = 0.f; av[j] = 0.f; }

#pragma unroll 4
  for (int k = 0; k < ND; ++k) {
    float4 xa = *(const float4*)&xs[k][half * 8];
    float4 xb = *(const float4*)&xs[k][half * 8 + 4];
    float wqv = wq[k * ND + o];
    float wkv = wk[k * ND + o];
    float wvv = wv[k * ND + o];
    aq[0] = fmaf(xa.x, wqv, aq[0]); aq[1] = fmaf(xa.y, wqv, aq[1]);
    aq[2] = fmaf(xa.z, wqv, aq[2]); aq[3] = fmaf(xa.w, wqv, aq[3]);
    aq[4] = fmaf(xb.x, wqv, aq[4]); aq[5] = fmaf(xb.y, wqv, aq[5]);
    aq[6] = fmaf(xb.z, wqv, aq[6]); aq[7] = fmaf(xb.w, wqv, aq[7]);
    ak[0] = fmaf(xa.x, wkv, ak[0]); ak[1] = fmaf(xa.y, wkv, ak[1]);
    ak[2] = fmaf(xa.z, wkv, ak[2]); ak[3] = fmaf(xa.w, wkv, ak[3]);
    ak[4] = fmaf(xb.x, wkv, ak[4]); ak[5] = fmaf(xb.y, wkv, ak[5]);
    ak[6] = fmaf(xb.z, wkv, ak[6]); ak[7] = fmaf(xb.w, wkv, ak[7]);
    av[0] = fmaf(xa.x, wvv, av[0]); av[1] = fmaf(xa.y, wvv, av[1]);
    av[2] = fmaf(xa.z, wvv, av[2]); av[3] = fmaf(xa.w, wvv, av[3]);
    av[4] = fmaf(xb.x, wvv, av[4]); av[5] = fmaf(xb.y, wvv, av[5]);
    av[6] = fmaf(xb.z, wvv, av[6]); av[7] = fmaf(xb.w, wvv, av[7]);
  }
  const float bqv = bq[o], bkv = bk[o], bvv = bv[o];
  const size_t base = (size_t)(r0 + half * 8) * ND + o;
#pragma unroll
  for (int j = 0; j < 8; ++j) {
    Q[base + (size_t)j * ND] = aq[j] + bqv;
    K[base + (size_t)j * ND] = ak[j] + bkv;
    V[base + (size_t)j * ND] = av[j] + bvv;
  }
}

// ---------------- out = msgn @ W + b: 16 rows/block ----------------
__global__ __launch_bounds__(256) void proj128(const float* __restrict__ x,
                                               const float* __restrict__ W,
                                               const float* __restrict__ b,
                                               float* __restrict__ y) {
  __shared__ float xs[ND][20];
  const int r0 = blockIdx.x * 16;
  const int tid = threadIdx.x;
  for (int i = tid; i < 16 * ND; i += 256) {
    int r = i >> 7, c = i & 127;
    xs[c][r] = x[(size_t)(r0 + r) * ND + c];
  }
  __syncthreads();
  const int o = tid & 127;
  const int half = tid >> 7;
  float a[8];
#pragma unroll
  for (int j = 0; j < 8; ++j) a[j] = 0.f;
#pragma unroll 8
  for (int k = 0; k < ND; ++k) {
    float4 xa = *(const float4*)&xs[k][half * 8];
    float4 xb = *(const float4*)&xs[k][half * 8 + 4];
    float w = W[k * ND + o];
    a[0] = fmaf(xa.x, w, a[0]); a[1] = fmaf(xa.y, w, a[1]);
    a[2] = fmaf(xa.z, w, a[2]); a[3] = fmaf(xa.w, w, a[3]);
    a[4] = fmaf(xb.x, w, a[4]); a[5] = fmaf(xb.y, w, a[5]);
    a[6] = fmaf(xb.z, w, a[6]); a[7] = fmaf(xb.w, w, a[7]);
  }
  const float bb = b[o];
  const size_t base = (size_t)(r0 + half * 8) * ND + o;
#pragma unroll
  for (int j = 0; j < 8; ++j) y[base + (size_t)j * ND] = a[j] + bb;
}

// ---------------- G[n,h,j] = Q[n,h,:]·we[j,h*16:+16], SB[n,h] = Q[n,h,:]·be_h ----
// block: 16 nodes; thread (h = tid>>5, j2 = tid&31) computes j = 2*j2, 2*j2+1.
__global__ __launch_bounds__(256) void k_gmat(const float* __restrict__ Q,
                                              const float* __restrict__ we,
                                              const float* __restrict__ be,
                                              __half2* __restrict__ G16,
                                              float* __restrict__ SB) {
  __shared__ float qs[16][ND];
  const int r0 = blockIdx.x * 16;
  const int tid = threadIdx.x;
  for (int i = tid; i < 16 * ND; i += 256) {
    int r = i >> 7, c = i & 127;
    qs[r][c] = Q[(size_t)(r0 + r) * ND + c];
  }
  __syncthreads();

  const int h = tid >> 5;
  const int j2 = tid & 31;
  const int j0 = j2 * 2;

  float4 w0[4], w1[4], bv[4];
#pragma unroll
  for (int i = 0; i < 4; ++i) {
    w0[i] = *(const float4*)(we + (size_t)j0 * ND + h * DK + i * 4);
    w1[i] = *(const float4*)(we + (size_t)(j0 + 1) * ND + h * DK + i * 4);
  }
  if (j2 == 0) {
#pragma unroll
    for (int i = 0; i < 4; ++i) bv[i] = *(const float4*)(be + h * DK + i * 4);
  }

  for (int r = 0; r < 16; ++r) {
    const float* qp = &qs[r][h * DK];
    float4 qa = *(const float4*)(qp + 0);
    float4 qb = *(const float4*)(qp + 4);
    float4 qc = *(const float4*)(qp + 8);
    float4 qd = *(const float4*)(qp + 12);

    float d0 = qa.x * w0[0].x;
    d0 = fmaf(qa.y, w0[0].y, d0); d0 = fmaf(qa.z, w0[0].z, d0); d0 = fmaf(qa.w, w0[0].w, d0);
    d0 = fmaf(qb.x, w0[1].x, d0); d0 = fmaf(qb.y, w0[1].y, d0);
    d0 = fmaf(qb.z, w0[1].z, d0); d0 = fmaf(qb.w, w0[1].w, d0);
    d0 = fmaf(qc.x, w0[2].x, d0); d0 = fmaf(qc.y, w0[2].y, d0);
    d0 = fmaf(qc.z, w0[2].z, d0); d0 = fmaf(qc.w, w0[2].w, d0);
    d0 = fmaf(qd.x, w0[3].x, d0); d0 = fmaf(qd.y, w0[3].y, d0);
    d0 = fmaf(qd.z, w0[3].z, d0); d0 = fmaf(qd.w, w0[3].w, d0);

    float d1 = qa.x * w1[0].x;
    d1 = fmaf(qa.y, w1[0].y, d1); d1 = fmaf(qa.z, w1[0].z, d1); d1 = fmaf(qa.w, w1[0].w, d1);
    d1 = fmaf(qb.x, w1[1].x, d1); d1 = fmaf(qb.y, w1[1].y, d1);
    d1 = fmaf(qb.z, w1[1].z, d1); d1 = fmaf(qb.w, w1[1].w, d1);
    d1 = fmaf(qc.x, w1[2].x, d1); d1 = fmaf(qc.y, w1[2].y, d1);
    d1 = fmaf(qc.z, w1[2].z, d1); d1 = fmaf(qc.w, w1[2].w, d1);
    d1 = fmaf(qd.x, w1[3].x, d1); d1 = fmaf(qd.y, w1[3].y, d1);
    d1 = fmaf(qd.z, w1[3].z, d1); d1 = fmaf(qd.w, w1[3].w, d1);

    G16[((size_t)(r0 + r) * 512 + h * 64 + j0) >> 1] = __floats2half2_rn(d0, d1);

    if (j2 == 0) {
      float s = qa.x * bv[0].x;
      s = fmaf(qa.y, bv[0].y, s); s = fmaf(qa.z, bv[0].z, s); s = fmaf(qa.w, bv[0].w, s);
      s = fmaf(qb.x, bv[1].x, s); s = fmaf(qb.y, bv[1].y, s);
      s = fmaf(qb.z, bv[1].z, s); s = fmaf(qb.w, bv[1].w, s);
      s = fmaf(qc.x, bv[2].x, s); s = fmaf(qc.y, bv[2].y, s);
      s = fmaf(qc.z, bv[2].z, s); s = fmaf(qc.w, bv[2].w, s);
      s = fmaf(qd.x, bv[3].x, s); s = fmaf(qd.y, bv[3].y, s);
      s = fmaf(qd.z, bv[3].z, s); s = fmaf(qd.w, bv[3].w, s);
      SB[(r0 + r) * NH + h] = s;
    }
  }
}

// ---------------- CSR build ----------------
__global__ __launch_bounds__(256) void k_hist(const int* __restrict__ ei,
                                              int* __restrict__ hist) {
  int e = blockIdx.x * 256 + threadIdx.x;
  if (e < NE) atomicAdd(&hist[ei[e]], 1);
}

__global__ __launch_bounds__(256) void k_scan1(const int* __restrict__ hist,
                                               int* __restrict__ off,
                                               int* __restrict__ bsum) {
  __shared__ int sh[256];
  const int tid = threadIdx.x;
  const int idx = blockIdx.x * 256 + tid;
  int v = (idx < NN) ? hist[idx] : 0;
  sh[tid] = v;
  __syncthreads();
#pragma unroll
  for (int d = 1; d < 256; d <<= 1) {
    int t = (tid >= d) ? sh[tid - d] : 0;
    __syncthreads();
    sh[tid] += t;
    __syncthreads();
  }
  if (idx < NN) off[idx] = sh[tid] - v;
  if (tid == 255) bsum[blockIdx.x] = sh[255];
}

__global__ __launch_bounds__(256) void k_scan2(int* __restrict__ bsum) {
  __shared__ int sh[256];
  const int tid = threadIdx.x;
  int v = (tid < SCAN_NBLK) ? bsum[tid] : 0;
  sh[tid] = v;
  __syncthreads();
#pragma unroll
  for (int d = 1; d < 256; d <<= 1) {
    int t = (tid >= d) ? sh[tid - d] : 0;
    __syncthreads();
    sh[tid] += t;
    __syncthreads();
  }
  if (tid < SCAN_NBLK) bsum[tid] = sh[tid] - v;
}

__global__ __launch_bounds__(256) void k_scan3(int* __restrict__ off,
                                               const int* __restrict__ bsum,
                                               int* __restrict__ cursor) {
  const int idx = blockIdx.x * 256 + threadIdx.x;
  if (idx < NN) {
    int o = off[idx] + bsum[blockIdx.x];
    off[idx] = o;
    cursor[idx] = o;
  }
  if (blockIdx.x == 0 && threadIdx.x == 0) off[NN] = NE;
}

__global__ __launch_bounds__(256) void k_scatter(const int* __restrict__ ei,
                                                 int* __restrict__ cursor,
                                                 int2* __restrict__ pair) {
  int e = blockIdx.x * 256 + threadIdx.x;
  if (e >= NE) return;
  int row = ei[e];
  int col = ei[NE + e];
  int pos = atomicAdd(&cursor[row], 1);
  pair[pos] = make_int2(col, e);
}

// ---------------- fused gather (R5 structure): 32 lanes/node, LDS ea staging ----
// USEG=true: setup read from precomputed G16/SB (6 loads). false: in-kernel.
template<bool USEG>
__global__ __launch_bounds__(256) void k_gather(const float* __restrict__ Q,
                                                const float* __restrict__ K,
                                                const float* __restrict__ V,
                                                const float* __restrict__ we,
                                                const float* __restrict__ be,
                                                const float* __restrict__ ea,
                                                const int* __restrict__ off,
                                                const int2* __restrict__ pair,
                                                const __half2* __restrict__ G16,
                                                const float* __restrict__ SB,
                                                float* __restrict__ msgn) {
  __shared__ float eas[8][8 * ED];   // 16 KB/block
  const int g = threadIdx.x >> 5;
  const int n = blockIdx.x * 8 + g;
  const int l = threadIdx.x & 31;
  const int h = l >> 2;
  const int q = l & 3;

  float gg[16];
  float4 qv;
  float sb;

  if (USEG) {
    qv = *(const float4*)(Q + (size_t)n * ND + h * DK + q * 4);
    sb = SB[n * NH + h] * 0.25f;
    const float4* gp = (const float4*)(G16 + (((size_t)n * 512 + h * 64 + q * 16) >> 1));
    float4 c0 = gp[0], c1 = gp[1];
    const __half2* h0 = (const __half2*)&c0;
    const __half2* h1 = (const __half2*)&c1;
#pragma unroll
    for (int i = 0; i < 4; ++i) {
      float2 f0 = __half22float2(h0[i]);
      gg[2 * i + 0] = f0.x; gg[2 * i + 1] = f0.y;
      float2 f1 = __half22float2(h1[i]);
      gg[8 + 2 * i + 0] = f1.x; gg[8 + 2 * i + 1] = f1.y;
    }
  } else {
    float qf[DK];
    const float4* qp = (const float4*)(Q + (size_t)n * ND + h * DK);
#pragma unroll
    for (int i = 0; i < 4; ++i) {
      float4 v = qp[i];
      qf[4 * i + 0] = v.x; qf[4 * i + 1] = v.y;
      qf[4 * i + 2] = v.z; qf[4 * i + 3] = v.w;
    }
    float sbase = 0.f;
    const float4* bp = (const float4*)(be + h * DK);
#pragma unroll
    for (int i = 0; i < 4; ++i) {
      float4 b = bp[i];
      sbase = fmaf(qf[4 * i + 0], b.x, sbase);
      sbase = fmaf(qf[4 * i + 1], b.y, sbase);
      sbase = fmaf(qf[4 * i + 2], b.z, sbase);
      sbase = fmaf(qf[4 * i + 3], b.w, sbase);
    }
    sb = sbase * 0.25f;
#pragma unroll
    for (int jj = 0; jj < 16; ++jj) {
      const float4* wp = (const float4*)(we + (size_t)(q * 16 + jj) * ND + h * DK);
      float s = 0.f;
#pragma unroll
      for (int i = 0; i < 4; ++i) {
        float4 w = wp[i];
        s = fmaf(qf[4 * i + 0], w.x, s);
        s = fmaf(qf[4 * i + 1], w.y, s);
        s = fmaf(qf[4 * i + 2], w.z, s);
        s = fmaf(qf[4 * i + 3], w.w, s);
      }
      gg[jj] = s;
    }
    qv.x = qf[q * 4 + 0]; qv.y = qf[q * 4 + 1];
    qv.z = qf[q * 4 + 2]; qv.w = qf[q * 4 + 3];
  }

  float4 acc = make_float4(0.f, 0.f, 0.f, 0.f);
  float den = 0.f;

  const int j0 = off[n], j1 = off[n + 1];
  const int hq = h * DK + q * 4;

  for (int jp = j0; jp < j1; jp += 8) {
    const int nc = min(8, j1 - jp);

    // --- stage: pair + ea chunk into LDS ---
    int2 p = make_int2(0, 0);
    if (l < nc) p = pair[jp + l];
    {
      const int eidx = __shfl(p.y, l >> 2, 32);
      if (l < 4 * nc) {
        const float4* src = (const float4*)(ea + (size_t)eidx * ED) + (l & 3);
        float4 a0 = src[0], a1 = src[4], a2 = src[8], a3 = src[12];
        float4* dst = (float4*)&eas[g][(l >> 2) * ED] + (l & 3);
        dst[0] = a0; dst[4] = a1; dst[8] = a2; dst[12] = a3;
      }
    }
    asm volatile("s_waitcnt lgkmcnt(0)" ::: "memory");
    __builtin_amdgcn_sched_barrier(0);

    int c = 0;
    for (; c + 4 <= nc; c += 4) {
      const int col0 = __shfl(p.x, c + 0, 32);
      const int col1 = __shfl(p.x, c + 1, 32);
      const int col2 = __shfl(p.x, c + 2, 32);
      const int col3 = __shfl(p.x, c + 3, 32);

      const float4 k0 = *(const float4*)(K + (size_t)col0 * ND + hq);
      const float4 k1 = *(const float4*)(K + (size_t)col1 * ND + hq);
      const float4 k2 = *(const float4*)(K + (size_t)col2 * ND + hq);
      const float4 k3 = *(const float4*)(K + (size_t)col3 * ND + hq);
      const float4 v0 = *(const float4*)(V + (size_t)col0 * ND + hq);
      const float4 v1 = *(const float4*)(V + (size_t)col1 * ND + hq);
      const float4 v2 = *(const float4*)(V + (size_t)col2 * ND + hq);
      const float4 v3 = *(const float4*)(V + (size_t)col3 * ND + hq);

      float s0 = k0.x * qv.x; s0 = fmaf(qv.y, k0.y, s0); s0 = fmaf(qv.z, k0.z, s0); s0 = fmaf(qv.w, k0.w, s0);
      float s1 = k1.x * qv.x; s1 = fmaf(qv.y, k1.y, s1); s1 = fmaf(qv.z, k1.z, s1); s1 = fmaf(qv.w, k1.w, s1);
      float s2 = k2.x * qv.x; s2 = fmaf(qv.y, k2.y, s2); s2 = fmaf(qv.z, k2.z, s2); s2 = fmaf(qv.w, k2.w, s2);
      float s3 = k3.x * qv.x; s3 = fmaf(qv.y, k3.y, s3); s3 = fmaf(qv.z, k3.z, s3); s3 = fmaf(qv.w, k3.w, s3);

      const float4* e0 = (const float4*)&eas[g][(c + 0) * ED + q * 16];
      const float4* e1 = (const float4*)&eas[g][(c + 1) * ED + q * 16];
      const float4* e2 = (const float4*)&eas[g][(c + 2) * ED + q * 16];
      const float4* e3 = (const float4*)&eas[g][(c + 3) * ED + q * 16];
#pragma unroll
      for (int i = 0; i < 4; ++i) {
        float4 a = e0[i];
        s0 = fmaf(a.x, gg[4 * i + 0], s0); s0 = fmaf(a.y, gg[4 * i + 1], s0);
        s0 = fmaf(a.z, gg[4 * i + 2], s0); s0 = fmaf(a.w, gg[4 * i + 3], s0);
      }
#pragma unroll
      for (int i = 0; i < 4; ++i) {
        float4 a = e1[i];
        s1 = fmaf(a.x, gg[4 * i + 0], s1); s1 = fmaf(a.y, gg[4 * i + 1], s1);
        s1 = fmaf(a.z, gg[4 * i + 2], s1); s1 = fmaf(a.w, gg[4 * i + 3], s1);
      }
#pragma unroll
      for (int i = 0; i < 4; ++i) {
        float4 a = e2[i];
        s2 = fmaf(a.x, gg[4 * i + 0], s2); s2 = fmaf(a.y, gg[4 * i + 1], s2);
        s2 = fmaf(a.z, gg[4 * i + 2], s2); s2 = fmaf(a.w, gg[4 * i + 3], s2);
      }
#pragma unroll
      for (int i = 0; i < 4; ++i) {
        float4 a = e3[i];
        s3 = fmaf(a.x, gg[4 * i + 0], s3); s3 = fmaf(a.y, gg[4 * i + 1], s3);
        s3 = fmaf(a.z, gg[4 * i + 2], s3); s3 = fmaf(a.w, gg[4 * i + 3], s3);
      }

      s0 += __shfl_xor(s0, 1); s0 += __shfl_xor(s0, 2);
      s1 += __shfl_xor(s1, 1); s1 += __shfl_xor(s1, 2);
      s2 += __shfl_xor(s2, 1); s2 += __shfl_xor(s2, 2);
      s3 += __shfl_xor(s3, 1); s3 += __shfl_xor(s3, 2);

      const float es0 = __expf(fmaf(s0, 0.25f, sb));
      const float es1 = __expf(fmaf(s1, 0.25f, sb));
      const float es2 = __expf(fmaf(s2, 0.25f, sb));
      const float es3 = __expf(fmaf(s3, 0.25f, sb));
      den += (es0 + es1) + (es2 + es3);

      acc.x = fmaf(es0, v0.x, acc.x); acc.y = fmaf(es0, v0.y, acc.y);
      acc.z = fmaf(es0, v0.z, acc.z); acc.w = fmaf(es0, v0.w, acc.w);
      acc.x = fmaf(es1, v1.x, acc.x); acc.y = fmaf(es1, v1.y, acc.y);
      acc.z = fmaf(es1, v1.z, acc.z); acc.w = fmaf(es1, v1.w, acc.w);
      acc.x = fmaf(es2, v2.x, acc.x); acc.y = fmaf(es2, v2.y, acc.y);
      acc.z = fmaf(es2, v2.z, acc.z); acc.w = fmaf(es2, v2.w, acc.w);
      acc.x = fmaf(es3, v3.x, acc.x); acc.y = fmaf(es3, v3.y, acc.y);
      acc.z = fmaf(es3, v3.z, acc.z); acc.w = fmaf(es3, v3.w, acc.w);
    }

    for (; c < nc; ++c) {
      const int col = __shfl(p.x, c, 32);
      const float4 kv = *(const float4*)(K + (size_t)col * ND + hq);
      const float4 vv = *(const float4*)(V + (size_t)col * ND + hq);
      float s = kv.x * qv.x;
      s = fmaf(qv.y, kv.y, s); s = fmaf(qv.z, kv.z, s); s = fmaf(qv.w, kv.w, s);
      const float4* ep = (const float4*)&eas[g][c * ED + q * 16];
#pragma unroll
      for (int i = 0; i < 4; ++i) {
        float4 a = ep[i];
        s = fmaf(a.x, gg[4 * i + 0], s); s = fmaf(a.y, gg[4 * i + 1], s);
        s = fmaf(a.z, gg[4 * i + 2], s); s = fmaf(a.w, gg[4 * i + 3], s);
      }
      s += __shfl_xor(s, 1); s += __shfl_xor(s, 2);
      const float es = __expf(fmaf(s, 0.25f, sb));
      den += es;
      acc.x = fmaf(es, vv.x, acc.x); acc.y = fmaf(es, vv.y, acc.y);
      acc.z = fmaf(es, vv.z, acc.z); acc.w = fmaf(es, vv.w, acc.w);
    }
  }

  const float inv = 1.f / (den + 1e-8f);
  float4 o;
  o.x = acc.x * inv; o.y = acc.y * inv; o.z = acc.z * inv; o.w = acc.w * inv;
  *(float4*)(msgn + (size_t)n * ND + h * DK + q * 4) = o;
}

extern "C" void kernel_launch(void* const* d_in, const int* in_sizes, int n_in,
                              void* d_out, int out_size, void* d_ws, size_t ws_size,
                              hipStream_t stream) {
  const float* nodes = (const float*)d_in[0];
  const int*   ei    = (const int*)d_in[1];
  const float* ea    = (const float*)d_in[2];
  const float* wq    = (const float*)d_in[3];
  const float* bq    = (const float*)d_in[4];
  const float* wk    = (const float*)d_in[5];
  const float* bk    = (const float*)d_in[6];
  const float* wv    = (const float*)d_in[7];
  const float* bv    = (const float*)d_in[8];
  const float* we    = (const float*)d_in[9];
  const float* be    = (const float*)d_in[10];
  const float* wo    = (const float*)d_in[11];
  const float* bo    = (const float*)d_in[12];
  float* out = (float*)d_out;

  float* ws = (float*)d_ws;
  const size_t NND = (size_t)NN * ND;
  float* Q    = ws;
  float* K    = Q + NND;
  float* V    = K + NND;
  float* msgn = V + NND;
  int* hist   = (int*)(msgn + NND);
  int* off    = hist + NN;            // NN+1 (padded to 40004)
  int* cursor = off + 40004;
  int* bsum   = cursor + NN;
  int2* pair  = (int2*)(bsum + 256);  // NE int2
  float* SB   = (float*)(pair + NE);  // NN*NH floats
  __half2* G16 = (__half2*)(SB + (size_t)NN * NH);  // NN*512 halfs

  // bytes needed through end of G16
  const size_t NEED = ((char*)(G16 + (size_t)NN * 256)) - (char*)d_ws;
  const bool useg = (ws_size >= NEED);

  hipMemsetAsync(hist, 0, NN * sizeof(int), stream);

  dim3 blk(256);

  proj_qkv<<<dim3(NN / 16), blk, 0, stream>>>(nodes, wq, bq, wk, bk, wv, bv, Q, K, V);

  dim3 gE((NE + 255) / 256);
  k_hist<<<gE, blk, 0, stream>>>(ei, hist);
  k_scan1<<<dim3(SCAN_NBLK), blk, 0, stream>>>(hist, off, bsum);
  k_scan2<<<dim3(1), blk, 0, stream>>>(bsum);
  k_scan3<<<dim3(SCAN_NBLK), blk, 0, stream>>>(off, bsum, cursor);
  k_scatter<<<gE, blk, 0, stream>>>(ei, cursor, pair);

  if (useg) {
    k_gmat<<<dim3(NN / 16), blk, 0, stream>>>(Q, we, be, G16, SB);
    k_gather<true><<<dim3(NN / 8), blk, 0, stream>>>(Q, K, V, we, be, ea, off, pair, G16, SB, msgn);
  } else {
    k_gather<false><<<dim3(NN / 8), blk, 0, stream>>>(Q, K, V, we, be, ea, off, pair, G16, SB, msgn);
  }

  proj128<<<dim3(NN / 16), blk, 0, stream>>>(msgn, wo, bo, out);
}

// Round 10
// 278.780 us; speedup vs baseline: 3.6737x; 1.1177x over previous
//
#include <hip/hip_runtime.h>
#include <hip/hip_fp16.h>

#define NN  40000
#define NE  640000
#define ND  128
#define ED  64
#define NH  8
#define DK  16

#define SCAN_NBLK 157   // ceil(40000/256)

// ---------------- fused Q/K/V projection: Q fp32, K/V fp16 ----------------
__global__ __launch_bounds__(256) void proj_qkv(const float* __restrict__ x,
                                                const float* __restrict__ wq,
                                                const float* __restrict__ bq,
                                                const float* __restrict__ wk,
                                                const float* __restrict__ bk,
                                                const float* __restrict__ wv,
                                                const float* __restrict__ bv,
                                                float* __restrict__ Q,
                                                __half* __restrict__ K16,
                                                __half* __restrict__ V16) {
  __shared__ float xs[ND][20];
  const int r0 = blockIdx.x * 16;
  const int tid = threadIdx.x;
  for (int i = tid; i < 16 * ND; i += 256) {
    int r = i >> 7, c = i & 127;
    xs[c][r] = x[(size_t)(r0 + r) * ND + c];
  }
  __syncthreads();

  const int o = tid & 127;
  const int half = tid >> 7;
  float aq[8], ak[8], av[8];
#pragma unroll
  for (int j = 0; j < 8; ++j) { aq[j] = 0.f; ak[j] = 0.f; av[j] = 0.f; }

#pragma unroll 4
  for (int k = 0; k < ND; ++k) {
    float4 xa = *(const float4*)&xs[k][half * 8];
    float4 xb = *(const float4*)&xs[k][half * 8 + 4];
    float wqv = wq[k * ND + o];
    float wkv = wk[k * ND + o];
    float wvv = wv[k * ND + o];
    aq[0] = fmaf(xa.x, wqv, aq[0]); aq[1] = fmaf(xa.y, wqv, aq[1]);
    aq[2] = fmaf(xa.z, wqv, aq[2]); aq[3] = fmaf(xa.w, wqv, aq[3]);
    aq[4] = fmaf(xb.x, wqv, aq[4]); aq[5] = fmaf(xb.y, wqv, aq[5]);
    aq[6] = fmaf(xb.z, wqv, aq[6]); aq[7] = fmaf(xb.w, wqv, aq[7]);
    ak[0] = fmaf(xa.x, wkv, ak[0]); ak[1] = fmaf(xa.y, wkv, ak[1]);
    ak[2] = fmaf(xa.z, wkv, ak[2]); ak[3] = fmaf(xa.w, wkv, ak[3]);
    ak[4] = fmaf(xb.x, wkv, ak[4]); ak[5] = fmaf(xb.y, wkv, ak[5]);
    ak[6] = fmaf(xb.z, wkv, ak[6]); ak[7] = fmaf(xb.w, wkv, ak[7]);
    av[0] = fmaf(xa.x, wvv, av[0]); av[1] = fmaf(xa.y, wvv, av[1]);
    av[2] = fmaf(xa.z, wvv, av[2]); av[3] = fmaf(xa.w, wvv, av[3]);
    av[4] = fmaf(xb.x, wvv, av[4]); av[5] = fmaf(xb.y, wvv, av[5]);
    av[6] = fmaf(xb.z, wvv, av[6]); av[7] = fmaf(xb.w, wvv, av[7]);
  }
  const float bqv = bq[o], bkv = bk[o], bvv = bv[o];
  const size_t base = (size_t)(r0 + half * 8) * ND + o;
#pragma unroll
  for (int j = 0; j < 8; ++j) {
    Q[base + (size_t)j * ND]   = aq[j] + bqv;
    K16[base + (size_t)j * ND] = __float2half_rn(ak[j] + bkv);
    V16[base + (size_t)j * ND] = __float2half_rn(av[j] + bvv);
  }
}

// ---------------- out = msgn @ W + b: 16 rows/block ----------------
__global__ __launch_bounds__(256) void proj128(const float* __restrict__ x,
                                               const float* __restrict__ W,
                                               const float* __restrict__ b,
                                               float* __restrict__ y) {
  __shared__ float xs[ND][20];
  const int r0 = blockIdx.x * 16;
  const int tid = threadIdx.x;
  for (int i = tid; i < 16 * ND; i += 256) {
    int r = i >> 7, c = i & 127;
    xs[c][r] = x[(size_t)(r0 + r) * ND + c];
  }
  __syncthreads();
  const int o = tid & 127;
  const int half = tid >> 7;
  float a[8];
#pragma unroll
  for (int j = 0; j < 8; ++j) a[j] = 0.f;
#pragma unroll 8
  for (int k = 0; k < ND; ++k) {
    float4 xa = *(const float4*)&xs[k][half * 8];
    float4 xb = *(const float4*)&xs[k][half * 8 + 4];
    float w = W[k * ND + o];
    a[0] = fmaf(xa.x, w, a[0]); a[1] = fmaf(xa.y, w, a[1]);
    a[2] = fmaf(xa.z, w, a[2]); a[3] = fmaf(xa.w, w, a[3]);
    a[4] = fmaf(xb.x, w, a[4]); a[5] = fmaf(xb.y, w, a[5]);
    a[6] = fmaf(xb.z, w, a[6]); a[7] = fmaf(xb.w, w, a[7]);
  }
  const float bb = b[o];
  const size_t base = (size_t)(r0 + half * 8) * ND + o;
#pragma unroll
  for (int j = 0; j < 8; ++j) y[base + (size_t)j * ND] = a[j] + bb;
}

// ---------------- G[n,h,j] = Q[n,h,:]·we[j,h*16:+16], SB[n,h] = Q[n,h,:]·be_h ----
__global__ __launch_bounds__(256) void k_gmat(const float* __restrict__ Q,
                                              const float* __restrict__ we,
                                              const float* __restrict__ be,
                                              __half2* __restrict__ G16,
                                              float* __restrict__ SB) {
  __shared__ float qs[16][ND];
  const int r0 = blockIdx.x * 16;
  const int tid = threadIdx.x;
  for (int i = tid; i < 16 * ND; i += 256) {
    int r = i >> 7, c = i & 127;
    qs[r][c] = Q[(size_t)(r0 + r) * ND + c];
  }
  __syncthreads();

  const int h = tid >> 5;
  const int j2 = tid & 31;
  const int j0 = j2 * 2;

  float4 w0[4], w1[4], bv[4];
#pragma unroll
  for (int i = 0; i < 4; ++i) {
    w0[i] = *(const float4*)(we + (size_t)j0 * ND + h * DK + i * 4);
    w1[i] = *(const float4*)(we + (size_t)(j0 + 1) * ND + h * DK + i * 4);
  }
  if (j2 == 0) {
#pragma unroll
    for (int i = 0; i < 4; ++i) bv[i] = *(const float4*)(be + h * DK + i * 4);
  }

  for (int r = 0; r < 16; ++r) {
    const float* qp = &qs[r][h * DK];
    float4 qa = *(const float4*)(qp + 0);
    float4 qb = *(const float4*)(qp + 4);
    float4 qc = *(const float4*)(qp + 8);
    float4 qd = *(const float4*)(qp + 12);

    float d0 = qa.x * w0[0].x;
    d0 = fmaf(qa.y, w0[0].y, d0); d0 = fmaf(qa.z, w0[0].z, d0); d0 = fmaf(qa.w, w0[0].w, d0);
    d0 = fmaf(qb.x, w0[1].x, d0); d0 = fmaf(qb.y, w0[1].y, d0);
    d0 = fmaf(qb.z, w0[1].z, d0); d0 = fmaf(qb.w, w0[1].w, d0);
    d0 = fmaf(qc.x, w0[2].x, d0); d0 = fmaf(qc.y, w0[2].y, d0);
    d0 = fmaf(qc.z, w0[2].z, d0); d0 = fmaf(qc.w, w0[2].w, d0);
    d0 = fmaf(qd.x, w0[3].x, d0); d0 = fmaf(qd.y, w0[3].y, d0);
    d0 = fmaf(qd.z, w0[3].z, d0); d0 = fmaf(qd.w, w0[3].w, d0);

    float d1 = qa.x * w1[0].x;
    d1 = fmaf(qa.y, w1[0].y, d1); d1 = fmaf(qa.z, w1[0].z, d1); d1 = fmaf(qa.w, w1[0].w, d1);
    d1 = fmaf(qb.x, w1[1].x, d1); d1 = fmaf(qb.y, w1[1].y, d1);
    d1 = fmaf(qb.z, w1[1].z, d1); d1 = fmaf(qb.w, w1[1].w, d1);
    d1 = fmaf(qc.x, w1[2].x, d1); d1 = fmaf(qc.y, w1[2].y, d1);
    d1 = fmaf(qc.z, w1[2].z, d1); d1 = fmaf(qc.w, w1[2].w, d1);
    d1 = fmaf(qd.x, w1[3].x, d1); d1 = fmaf(qd.y, w1[3].y, d1);
    d1 = fmaf(qd.z, w1[3].z, d1); d1 = fmaf(qd.w, w1[3].w, d1);

    G16[((size_t)(r0 + r) * 512 + h * 64 + j0) >> 1] = __floats2half2_rn(d0, d1);

    if (j2 == 0) {
      float s = qa.x * bv[0].x;
      s = fmaf(qa.y, bv[0].y, s); s = fmaf(qa.z, bv[0].z, s); s = fmaf(qa.w, bv[0].w, s);
      s = fmaf(qb.x, bv[1].x, s); s = fmaf(qb.y, bv[1].y, s);
      s = fmaf(qb.z, bv[1].z, s); s = fmaf(qb.w, bv[1].w, s);
      s = fmaf(qc.x, bv[2].x, s); s = fmaf(qc.y, bv[2].y, s);
      s = fmaf(qc.z, bv[2].z, s); s = fmaf(qc.w, bv[2].w, s);
      s = fmaf(qd.x, bv[3].x, s); s = fmaf(qd.y, bv[3].y, s);
      s = fmaf(qd.z, bv[3].z, s); s = fmaf(qd.w, bv[3].w, s);
      SB[(r0 + r) * NH + h] = s;
    }
  }
}

// ---------------- CSR build ----------------
__global__ __launch_bounds__(256) void k_hist(const int* __restrict__ ei,
                                              int* __restrict__ hist) {
  int e = blockIdx.x * 256 + threadIdx.x;
  if (e < NE) atomicAdd(&hist[ei[e]], 1);
}

__global__ __launch_bounds__(256) void k_scan1(const int* __restrict__ hist,
                                               int* __restrict__ off,
                                               int* __restrict__ bsum) {
  __shared__ int sh[256];
  const int tid = threadIdx.x;
  const int idx = blockIdx.x * 256 + tid;
  int v = (idx < NN) ? hist[idx] : 0;
  sh[tid] = v;
  __syncthreads();
#pragma unroll
  for (int d = 1; d < 256; d <<= 1) {
    int t = (tid >= d) ? sh[tid - d] : 0;
    __syncthreads();
    sh[tid] += t;
    __syncthreads();
  }
  if (idx < NN) off[idx] = sh[tid] - v;
  if (tid == 255) bsum[blockIdx.x] = sh[255];
}

__global__ __launch_bounds__(256) void k_scan2(int* __restrict__ bsum) {
  __shared__ int sh[256];
  const int tid = threadIdx.x;
  int v = (tid < SCAN_NBLK) ? bsum[tid] : 0;
  sh[tid] = v;
  __syncthreads();
#pragma unroll
  for (int d = 1; d < 256; d <<= 1) {
    int t = (tid >= d) ? sh[tid - d] : 0;
    __syncthreads();
    sh[tid] += t;
    __syncthreads();
  }
  if (tid < SCAN_NBLK) bsum[tid] = sh[tid] - v;
}

__global__ __launch_bounds__(256) void k_scan3(int* __restrict__ off,
                                               const int* __restrict__ bsum,
                                               int* __restrict__ cursor) {
  const int idx = blockIdx.x * 256 + threadIdx.x;
  if (idx < NN) {
    int o = off[idx] + bsum[blockIdx.x];
    off[idx] = o;
    cursor[idx] = o;
  }
  if (blockIdx.x == 0 && threadIdx.x == 0) off[NN] = NE;
}

__global__ __launch_bounds__(256) void k_scatter(const int* __restrict__ ei,
                                                 int* __restrict__ cursor,
                                                 int2* __restrict__ pair) {
  int e = blockIdx.x * 256 + threadIdx.x;
  if (e >= NE) return;
  int row = ei[e];
  int col = ei[NE + e];
  int pos = atomicAdd(&cursor[row], 1);
  pair[pos] = make_int2(col, e);
}

// ---------------- fused gather: 32 lanes/node, fp16 K/V, LDS ea staging ----------
// per lane: K/V quarter = 4 halves (8B). Score reduce over q-group via shfl_xor.
#define LOADKV(col, KA, KB, VA, VB) \
  const float2 kr##KA = *(const float2*)(K16 + (size_t)(col) * ND + hq);        \
  const float2 vr##KA = *(const float2*)(V16 + (size_t)(col) * ND + hq);        \
  float2 KA, KB, VA, VB;                                                        \
  { const __half2* _h = (const __half2*)&kr##KA;                                \
    KA = __half22float2(_h[0]); KB = __half22float2(_h[1]); }                   \
  { const __half2* _h = (const __half2*)&vr##KA;                                \
    VA = __half22float2(_h[0]); VB = __half22float2(_h[1]); }

__global__ __launch_bounds__(256) void k_gather(const float* __restrict__ Q,
                                                const __half* __restrict__ K16,
                                                const __half* __restrict__ V16,
                                                const float* __restrict__ ea,
                                                const int* __restrict__ off,
                                                const int2* __restrict__ pair,
                                                const __half2* __restrict__ G16,
                                                const float* __restrict__ SB,
                                                float* __restrict__ msgn) {
  __shared__ float eas[8][8 * ED];   // 16 KB/block
  const int g = threadIdx.x >> 5;
  const int n = blockIdx.x * 8 + g;
  const int l = threadIdx.x & 31;
  const int h = l >> 2;
  const int q = l & 3;

  float gg[16];
  float4 qv = *(const float4*)(Q + (size_t)n * ND + h * DK + q * 4);
  const float sb = SB[n * NH + h] * 0.25f;
  {
    const float4* gp = (const float4*)(G16 + (((size_t)n * 512 + h * 64 + q * 16) >> 1));
    float4 c0 = gp[0], c1 = gp[1];
    const __half2* h0 = (const __half2*)&c0;
    const __half2* h1 = (const __half2*)&c1;
#pragma unroll
    for (int i = 0; i < 4; ++i) {
      float2 f0 = __half22float2(h0[i]);
      gg[2 * i + 0] = f0.x; gg[2 * i + 1] = f0.y;
      float2 f1 = __half22float2(h1[i]);
      gg[8 + 2 * i + 0] = f1.x; gg[8 + 2 * i + 1] = f1.y;
    }
  }

  float4 acc = make_float4(0.f, 0.f, 0.f, 0.f);
  float den = 0.f;

  const int j0 = off[n], j1 = off[n + 1];
  const int hq = h * DK + q * 4;

  for (int jp = j0; jp < j1; jp += 8) {
    const int nc = min(8, j1 - jp);

    // --- stage: pair + ea chunk into LDS ---
    int2 p = make_int2(0, 0);
    if (l < nc) p = pair[jp + l];
    {
      const int eidx = __shfl(p.y, l >> 2, 32);
      if (l < 4 * nc) {
        const float4* src = (const float4*)(ea + (size_t)eidx * ED) + (l & 3);
        float4 a0 = src[0], a1 = src[4], a2 = src[8], a3 = src[12];
        float4* dst = (float4*)&eas[g][(l >> 2) * ED] + (l & 3);
        dst[0] = a0; dst[4] = a1; dst[8] = a2; dst[12] = a3;
      }
    }
    asm volatile("s_waitcnt lgkmcnt(0)" ::: "memory");
    __builtin_amdgcn_sched_barrier(0);

    int c = 0;
    for (; c + 4 <= nc; c += 4) {
      const int col0 = __shfl(p.x, c + 0, 32);
      const int col1 = __shfl(p.x, c + 1, 32);
      const int col2 = __shfl(p.x, c + 2, 32);
      const int col3 = __shfl(p.x, c + 3, 32);

      LOADKV(col0, ka0, kb0, va0, vb0);
      LOADKV(col1, ka1, kb1, va1, vb1);
      LOADKV(col2, ka2, kb2, va2, vb2);
      LOADKV(col3, ka3, kb3, va3, vb3);

      float s0 = ka0.x * qv.x; s0 = fmaf(qv.y, ka0.y, s0); s0 = fmaf(qv.z, kb0.x, s0); s0 = fmaf(qv.w, kb0.y, s0);
      float s1 = ka1.x * qv.x; s1 = fmaf(qv.y, ka1.y, s1); s1 = fmaf(qv.z, kb1.x, s1); s1 = fmaf(qv.w, kb1.y, s1);
      float s2 = ka2.x * qv.x; s2 = fmaf(qv.y, ka2.y, s2); s2 = fmaf(qv.z, kb2.x, s2); s2 = fmaf(qv.w, kb2.y, s2);
      float s3 = ka3.x * qv.x; s3 = fmaf(qv.y, ka3.y, s3); s3 = fmaf(qv.z, kb3.x, s3); s3 = fmaf(qv.w, kb3.y, s3);

      const float4* e0 = (const float4*)&eas[g][(c + 0) * ED + q * 16];
      const float4* e1 = (const float4*)&eas[g][(c + 1) * ED + q * 16];
      const float4* e2 = (const float4*)&eas[g][(c + 2) * ED + q * 16];
      const float4* e3 = (const float4*)&eas[g][(c + 3) * ED + q * 16];
#pragma unroll
      for (int i = 0; i < 4; ++i) {
        float4 a = e0[i];
        s0 = fmaf(a.x, gg[4 * i + 0], s0); s0 = fmaf(a.y, gg[4 * i + 1], s0);
        s0 = fmaf(a.z, gg[4 * i + 2], s0); s0 = fmaf(a.w, gg[4 * i + 3], s0);
      }
#pragma unroll
      for (int i = 0; i < 4; ++i) {
        float4 a = e1[i];
        s1 = fmaf(a.x, gg[4 * i + 0], s1); s1 = fmaf(a.y, gg[4 * i + 1], s1);
        s1 = fmaf(a.z, gg[4 * i + 2], s1); s1 = fmaf(a.w, gg[4 * i + 3], s1);
      }
#pragma unroll
      for (int i = 0; i < 4; ++i) {
        float4 a = e2[i];
        s2 = fmaf(a.x, gg[4 * i + 0], s2); s2 = fmaf(a.y, gg[4 * i + 1], s2);
        s2 = fmaf(a.z, gg[4 * i + 2], s2); s2 = fmaf(a.w, gg[4 * i + 3], s2);
      }
#pragma unroll
      for (int i = 0; i < 4; ++i) {
        float4 a = e3[i];
        s3 = fmaf(a.x, gg[4 * i + 0], s3); s3 = fmaf(a.y, gg[4 * i + 1], s3);
        s3 = fmaf(a.z, gg[4 * i + 2], s3); s3 = fmaf(a.w, gg[4 * i + 3], s3);
      }

      s0 += __shfl_xor(s0, 1); s0 += __shfl_xor(s0, 2);
      s1 += __shfl_xor(s1, 1); s1 += __shfl_xor(s1, 2);
      s2 += __shfl_xor(s2, 1); s2 += __shfl_xor(s2, 2);
      s3 += __shfl_xor(s3, 1); s3 += __shfl_xor(s3, 2);

      const float es0 = __expf(fmaf(s0, 0.25f, sb));
      const float es1 = __expf(fmaf(s1, 0.25f, sb));
      const float es2 = __expf(fmaf(s2, 0.25f, sb));
      const float es3 = __expf(fmaf(s3, 0.25f, sb));
      den += (es0 + es1) + (es2 + es3);

      acc.x = fmaf(es0, va0.x, acc.x); acc.y = fmaf(es0, va0.y, acc.y);
      acc.z = fmaf(es0, vb0.x, acc.z); acc.w = fmaf(es0, vb0.y, acc.w);
      acc.x = fmaf(es1, va1.x, acc.x); acc.y = fmaf(es1, va1.y, acc.y);
      acc.z = fmaf(es1, vb1.x, acc.z); acc.w = fmaf(es1, vb1.y, acc.w);
      acc.x = fmaf(es2, va2.x, acc.x); acc.y = fmaf(es2, va2.y, acc.y);
      acc.z = fmaf(es2, vb2.x, acc.z); acc.w = fmaf(es2, vb2.y, acc.w);
      acc.x = fmaf(es3, va3.x, acc.x); acc.y = fmaf(es3, va3.y, acc.y);
      acc.z = fmaf(es3, vb3.x, acc.z); acc.w = fmaf(es3, vb3.y, acc.w);
    }

    for (; c < nc; ++c) {
      const int col = __shfl(p.x, c, 32);
      LOADKV(col, ka, kb, va, vb);
      float s = ka.x * qv.x;
      s = fmaf(qv.y, ka.y, s); s = fmaf(qv.z, kb.x, s); s = fmaf(qv.w, kb.y, s);
      const float4* ep = (const float4*)&eas[g][c * ED + q * 16];
#pragma unroll
      for (int i = 0; i < 4; ++i) {
        float4 a = ep[i];
        s = fmaf(a.x, gg[4 * i + 0], s); s = fmaf(a.y, gg[4 * i + 1], s);
        s = fmaf(a.z, gg[4 * i + 2], s); s = fmaf(a.w, gg[4 * i + 3], s);
      }
      s += __shfl_xor(s, 1); s += __shfl_xor(s, 2);
      const float es = __expf(fmaf(s, 0.25f, sb));
      den += es;
      acc.x = fmaf(es, va.x, acc.x); acc.y = fmaf(es, va.y, acc.y);
      acc.z = fmaf(es, vb.x, acc.z); acc.w = fmaf(es, vb.y, acc.w);
    }
  }

  const float inv = 1.f / (den + 1e-8f);
  float4 o;
  o.x = acc.x * inv; o.y = acc.y * inv; o.z = acc.z * inv; o.w = acc.w * inv;
  *(float4*)(msgn + (size_t)n * ND + h * DK + q * 4) = o;
}

extern "C" void kernel_launch(void* const* d_in, const int* in_sizes, int n_in,
                              void* d_out, int out_size, void* d_ws, size_t ws_size,
                              hipStream_t stream) {
  const float* nodes = (const float*)d_in[0];
  const int*   ei    = (const int*)d_in[1];
  const float* ea    = (const float*)d_in[2];
  const float* wq    = (const float*)d_in[3];
  const float* bq    = (const float*)d_in[4];
  const float* wk    = (const float*)d_in[5];
  const float* bk    = (const float*)d_in[6];
  const float* wv    = (const float*)d_in[7];
  const float* bv    = (const float*)d_in[8];
  const float* we    = (const float*)d_in[9];
  const float* be    = (const float*)d_in[10];
  const float* wo    = (const float*)d_in[11];
  const float* bo    = (const float*)d_in[12];
  float* out = (float*)d_out;

  float* ws = (float*)d_ws;
  const size_t NND = (size_t)NN * ND;
  float*  Q    = ws;                         // NND f32
  float*  msgn = Q + NND;                    // NND f32
  __half* K16  = (__half*)(msgn + NND);      // NND f16
  __half* V16  = K16 + NND;                  // NND f16
  int* hist    = (int*)(V16 + NND);          // NN
  int* off     = hist + NN;                  // 40004
  int* cursor  = off + 40004;                // NN
  int* bsum    = cursor + NN;                // 256
  int2* pair   = (int2*)(bsum + 256);        // NE (8B-aligned: word count even)
  float* SB    = (float*)(pair + NE);        // NN*NH f32
  __half2* G16 = (__half2*)(SB + (size_t)NN * NH);  // NN*512 f16 (16B-aligned)

  hipMemsetAsync(hist, 0, NN * sizeof(int), stream);

  dim3 blk(256);

  proj_qkv<<<dim3(NN / 16), blk, 0, stream>>>(nodes, wq, bq, wk, bk, wv, bv, Q, K16, V16);

  dim3 gE((NE + 255) / 256);
  k_hist<<<gE, blk, 0, stream>>>(ei, hist);
  k_scan1<<<dim3(SCAN_NBLK), blk, 0, stream>>>(hist, off, bsum);
  k_scan2<<<dim3(1), blk, 0, stream>>>(bsum);
  k_scan3<<<dim3(SCAN_NBLK), blk, 0, stream>>>(off, bsum, cursor);
  k_scatter<<<gE, blk, 0, stream>>>(ei, cursor, pair);

  k_gmat<<<dim3(NN / 16), blk, 0, stream>>>(Q, we, be, G16, SB);

  k_gather<<<dim3(NN / 8), blk, 0, stream>>>(Q, K16, V16, ea, off, pair, G16, SB, msgn);

  proj128<<<dim3(NN / 16), blk, 0, stream>>>(msgn, wo, bo, out);
}

// Round 11
// 264.985 us; speedup vs baseline: 3.8650x; 1.0521x over previous
//
#include <hip/hip_runtime.h>
#include <hip/hip_fp16.h>

#define NN  40000
#define NE  640000
#define ND  128
#define ED  64
#define NH  8
#define DK  16

#define SCAN_NBLK 157   // ceil(40000/256)

// ------- fused Q/K/V projection + G/SB precompute: 16 rows/block ----------
// Phase 1: y = x@W+b for Q(f32), K/V(f16). Phase 2 (same block, Q in LDS):
// G[n,h,j] = 0.25*Q[n,h,:]·we[j,h*16:+16] (fp16), SB[n,h] = 0.25*Q[n,h,:]·be_h.
__global__ __launch_bounds__(256) void proj_qkv_g(const float* __restrict__ x,
                                                  const float* __restrict__ wq,
                                                  const float* __restrict__ bq,
                                                  const float* __restrict__ wk,
                                                  const float* __restrict__ bk,
                                                  const float* __restrict__ wv,
                                                  const float* __restrict__ bv,
                                                  const float* __restrict__ we,
                                                  const float* __restrict__ be,
                                                  float* __restrict__ Q,
                                                  __half* __restrict__ K16,
                                                  __half* __restrict__ V16,
                                                  __half2* __restrict__ G16,
                                                  float* __restrict__ SB) {
  __shared__ float xs[ND][20];
  __shared__ float qs[16][ND];
  const int r0 = blockIdx.x * 16;
  const int tid = threadIdx.x;
  for (int i = tid; i < 16 * ND; i += 256) {
    int r = i >> 7, c = i & 127;
    xs[c][r] = x[(size_t)(r0 + r) * ND + c];
  }
  __syncthreads();

  const int o = tid & 127;
  const int half = tid >> 7;
  float aq[8], ak[8], av[8];
#pragma unroll
  for (int j = 0; j < 8; ++j) { aq[j] = 0.f; ak[j] = 0.f; av[j] = 0.f; }

#pragma unroll 4
  for (int k = 0; k < ND; ++k) {
    float4 xa = *(const float4*)&xs[k][half * 8];
    float4 xb = *(const float4*)&xs[k][half * 8 + 4];
    float wqv = wq[k * ND + o];
    float wkv = wk[k * ND + o];
    float wvv = wv[k * ND + o];
    aq[0] = fmaf(xa.x, wqv, aq[0]); aq[1] = fmaf(xa.y, wqv, aq[1]);
    aq[2] = fmaf(xa.z, wqv, aq[2]); aq[3] = fmaf(xa.w, wqv, aq[3]);
    aq[4] = fmaf(xb.x, wqv, aq[4]); aq[5] = fmaf(xb.y, wqv, aq[5]);
    aq[6] = fmaf(xb.z, wqv, aq[6]); aq[7] = fmaf(xb.w, wqv, aq[7]);
    ak[0] = fmaf(xa.x, wkv, ak[0]); ak[1] = fmaf(xa.y, wkv, ak[1]);
    ak[2] = fmaf(xa.z, wkv, ak[2]); ak[3] = fmaf(xa.w, wkv, ak[3]);
    ak[4] = fmaf(xb.x, wkv, ak[4]); ak[5] = fmaf(xb.y, wkv, ak[5]);
    ak[6] = fmaf(xb.z, wkv, ak[6]); ak[7] = fmaf(xb.w, wkv, ak[7]);
    av[0] = fmaf(xa.x, wvv, av[0]); av[1] = fmaf(xa.y, wvv, av[1]);
    av[2] = fmaf(xa.z, wvv, av[2]); av[3] = fmaf(xa.w, wvv, av[3]);
    av[4] = fmaf(xb.x, wvv, av[4]); av[5] = fmaf(xb.y, wvv, av[5]);
    av[6] = fmaf(xb.z, wvv, av[6]); av[7] = fmaf(xb.w, wvv, av[7]);
  }
  const float bqv = bq[o], bkv = bk[o], bvv = bv[o];
  const size_t base = (size_t)(r0 + half * 8) * ND + o;
#pragma unroll
  for (int j = 0; j < 8; ++j) {
    const float qj = aq[j] + bqv;
    Q[base + (size_t)j * ND] = qj;
    qs[half * 8 + j][o] = qj;                 // bank = o%32 -> 2-way, free
    K16[base + (size_t)j * ND] = __float2half_rn(ak[j] + bkv);
    V16[base + (size_t)j * ND] = __float2half_rn(av[j] + bvv);
  }
  __syncthreads();

  // ---- phase 2: gmat ----
  const int h2 = tid >> 5;
  const int j2 = tid & 31;
  const int jj = j2 * 2;

  float4 w0[4], w1[4], bv4[4];
#pragma unroll
  for (int i = 0; i < 4; ++i) {
    w0[i] = *(const float4*)(we + (size_t)jj * ND + h2 * DK + i * 4);
    w1[i] = *(const float4*)(we + (size_t)(jj + 1) * ND + h2 * DK + i * 4);
  }
  if (j2 == 0) {
#pragma unroll
    for (int i = 0; i < 4; ++i) bv4[i] = *(const float4*)(be + h2 * DK + i * 4);
  }

  for (int r = 0; r < 16; ++r) {
    const float* qp = &qs[r][h2 * DK];
    float4 qa = *(const float4*)(qp + 0);
    float4 qb = *(const float4*)(qp + 4);
    float4 qc = *(const float4*)(qp + 8);
    float4 qd = *(const float4*)(qp + 12);

    float d0 = qa.x * w0[0].x;
    d0 = fmaf(qa.y, w0[0].y, d0); d0 = fmaf(qa.z, w0[0].z, d0); d0 = fmaf(qa.w, w0[0].w, d0);
    d0 = fmaf(qb.x, w0[1].x, d0); d0 = fmaf(qb.y, w0[1].y, d0);
    d0 = fmaf(qb.z, w0[1].z, d0); d0 = fmaf(qb.w, w0[1].w, d0);
    d0 = fmaf(qc.x, w0[2].x, d0); d0 = fmaf(qc.y, w0[2].y, d0);
    d0 = fmaf(qc.z, w0[2].z, d0); d0 = fmaf(qc.w, w0[2].w, d0);
    d0 = fmaf(qd.x, w0[3].x, d0); d0 = fmaf(qd.y, w0[3].y, d0);
    d0 = fmaf(qd.z, w0[3].z, d0); d0 = fmaf(qd.w, w0[3].w, d0);

    float d1 = qa.x * w1[0].x;
    d1 = fmaf(qa.y, w1[0].y, d1); d1 = fmaf(qa.z, w1[0].z, d1); d1 = fmaf(qa.w, w1[0].w, d1);
    d1 = fmaf(qb.x, w1[1].x, d1); d1 = fmaf(qb.y, w1[1].y, d1);
    d1 = fmaf(qb.z, w1[1].z, d1); d1 = fmaf(qb.w, w1[1].w, d1);
    d1 = fmaf(qc.x, w1[2].x, d1); d1 = fmaf(qc.y, w1[2].y, d1);
    d1 = fmaf(qc.z, w1[2].z, d1); d1 = fmaf(qc.w, w1[2].w, d1);
    d1 = fmaf(qd.x, w1[3].x, d1); d1 = fmaf(qd.y, w1[3].y, d1);
    d1 = fmaf(qd.z, w1[3].z, d1); d1 = fmaf(qd.w, w1[3].w, d1);

    G16[((size_t)(r0 + r) * 512 + h2 * 64 + jj) >> 1] =
        __floats2half2_rn(d0 * 0.25f, d1 * 0.25f);

    if (j2 == 0) {
      float s = qa.x * bv4[0].x;
      s = fmaf(qa.y, bv4[0].y, s); s = fmaf(qa.z, bv4[0].z, s); s = fmaf(qa.w, bv4[0].w, s);
      s = fmaf(qb.x, bv4[1].x, s); s = fmaf(qb.y, bv4[1].y, s);
      s = fmaf(qb.z, bv4[1].z, s); s = fmaf(qb.w, bv4[1].w, s);
      s = fmaf(qc.x, bv4[2].x, s); s = fmaf(qc.y, bv4[2].y, s);
      s = fmaf(qc.z, bv4[2].z, s); s = fmaf(qc.w, bv4[2].w, s);
      s = fmaf(qd.x, bv4[3].x, s); s = fmaf(qd.y, bv4[3].y, s);
      s = fmaf(qd.z, bv4[3].z, s); s = fmaf(qd.w, bv4[3].w, s);
      SB[(r0 + r) * NH + h2] = s * 0.25f;
    }
  }
}

// ---------------- out = msgn @ W + b: 16 rows/block ----------------
__global__ __launch_bounds__(256) void proj128(const float* __restrict__ x,
                                               const float* __restrict__ W,
                                               const float* __restrict__ b,
                                               float* __restrict__ y) {
  __shared__ float xs[ND][20];
  const int r0 = blockIdx.x * 16;
  const int tid = threadIdx.x;
  for (int i = tid; i < 16 * ND; i += 256) {
    int r = i >> 7, c = i & 127;
    xs[c][r] = x[(size_t)(r0 + r) * ND + c];
  }
  __syncthreads();
  const int o = tid & 127;
  const int half = tid >> 7;
  float a[8];
#pragma unroll
  for (int j = 0; j < 8; ++j) a[j] = 0.f;
#pragma unroll 8
  for (int k = 0; k < ND; ++k) {
    float4 xa = *(const float4*)&xs[k][half * 8];
    float4 xb = *(const float4*)&xs[k][half * 8 + 4];
    float w = W[k * ND + o];
    a[0] = fmaf(xa.x, w, a[0]); a[1] = fmaf(xa.y, w, a[1]);
    a[2] = fmaf(xa.z, w, a[2]); a[3] = fmaf(xa.w, w, a[3]);
    a[4] = fmaf(xb.x, w, a[4]); a[5] = fmaf(xb.y, w, a[5]);
    a[6] = fmaf(xb.z, w, a[6]); a[7] = fmaf(xb.w, w, a[7]);
  }
  const float bb = b[o];
  const size_t base = (size_t)(r0 + half * 8) * ND + o;
#pragma unroll
  for (int j = 0; j < 8; ++j) y[base + (size_t)j * ND] = a[j] + bb;
}

// ---------------- CSR build ----------------
__global__ __launch_bounds__(256) void k_hist(const int* __restrict__ ei,
                                              int* __restrict__ hist) {
  int e = blockIdx.x * 256 + threadIdx.x;
  if (e < NE) atomicAdd(&hist[ei[e]], 1);
}

__global__ __launch_bounds__(256) void k_scan1(const int* __restrict__ hist,
                                               int* __restrict__ off,
                                               int* __restrict__ bsum) {
  __shared__ int sh[256];
  const int tid = threadIdx.x;
  const int idx = blockIdx.x * 256 + tid;
  int v = (idx < NN) ? hist[idx] : 0;
  sh[tid] = v;
  __syncthreads();
#pragma unroll
  for (int d = 1; d < 256; d <<= 1) {
    int t = (tid >= d) ? sh[tid - d] : 0;
    __syncthreads();
    sh[tid] += t;
    __syncthreads();
  }
  if (idx < NN) off[idx] = sh[tid] - v;
  if (tid == 255) bsum[blockIdx.x] = sh[255];
}

__global__ __launch_bounds__(256) void k_scan2(int* __restrict__ bsum) {
  __shared__ int sh[256];
  const int tid = threadIdx.x;
  int v = (tid < SCAN_NBLK) ? bsum[tid] : 0;
  sh[tid] = v;
  __syncthreads();
#pragma unroll
  for (int d = 1; d < 256; d <<= 1) {
    int t = (tid >= d) ? sh[tid - d] : 0;
    __syncthreads();
    sh[tid] += t;
    __syncthreads();
  }
  if (tid < SCAN_NBLK) bsum[tid] = sh[tid] - v;
}

__global__ __launch_bounds__(256) void k_scan3(int* __restrict__ off,
                                               const int* __restrict__ bsum,
                                               int* __restrict__ cursor) {
  const int idx = blockIdx.x * 256 + threadIdx.x;
  if (idx < NN) {
    int o = off[idx] + bsum[blockIdx.x];
    off[idx] = o;
    cursor[idx] = o;
  }
  if (blockIdx.x == 0 && threadIdx.x == 0) off[NN] = NE;
}

__global__ __launch_bounds__(256) void k_scatter(const int* __restrict__ ei,
                                                 int* __restrict__ cursor,
                                                 int2* __restrict__ pair) {
  int e = blockIdx.x * 256 + threadIdx.x;
  if (e >= NE) return;
  int row = ei[e];
  int col = ei[NE + e];
  int pos = atomicAdd(&cursor[row], 1);
  pair[pos] = make_int2(col, e);
}

// ---------------- fused gather: pipelined, fp16 K/V, prescaled G/SB ------------
// 32 lanes/node. Chunk = 8 edges. State carried across iterations:
//   p  = pair(t)   (consumed for K/V cols)
//   er = ea(t)     in regs (ds_written at iter start)
//   pn = pair(t+1) (feeds ea(t+1) prefetch)
// All prefetch indices clamped to jlast -> dup L1 hits, no masks needed except
// the es validity mask. Scores/G/SB pre-scaled by 0.25.
#define LOADKV(col, KA, KB, VA, VB) \
  const float2 kr##KA = *(const float2*)(K16 + (size_t)(col) * ND + hq);        \
  const float2 vr##KA = *(const float2*)(V16 + (size_t)(col) * ND + hq);        \
  float2 KA, KB, VA, VB;                                                        \
  { const __half2* _h = (const __half2*)&kr##KA;                                \
    KA = __half22float2(_h[0]); KB = __half22float2(_h[1]); }                   \
  { const __half2* _h = (const __half2*)&vr##KA;                                \
    VA = __half22float2(_h[0]); VB = __half22float2(_h[1]); }

__global__ __launch_bounds__(256) void k_gather(const float* __restrict__ Q,
                                                const __half* __restrict__ K16,
                                                const __half* __restrict__ V16,
                                                const float* __restrict__ ea,
                                                const int* __restrict__ off,
                                                const int2* __restrict__ pair,
                                                const __half2* __restrict__ G16,
                                                const float* __restrict__ SB,
                                                float* __restrict__ msgn) {
  __shared__ float eas[8][8 * ED];   // 16 KB/block
  const int g = threadIdx.x >> 5;
  const int n = blockIdx.x * 8 + g;
  const int l = threadIdx.x & 31;
  const int h = l >> 2;
  const int q = l & 3;

  float gg[16];
  float4 qv = *(const float4*)(Q + (size_t)n * ND + h * DK + q * 4);
  qv.x *= 0.25f; qv.y *= 0.25f; qv.z *= 0.25f; qv.w *= 0.25f;
  const float sb = SB[n * NH + h];   // already x0.25
  {
    const float4* gp = (const float4*)(G16 + (((size_t)n * 512 + h * 64 + q * 16) >> 1));
    float4 c0 = gp[0], c1 = gp[1];
    const __half2* h0 = (const __half2*)&c0;
    const __half2* h1 = (const __half2*)&c1;
#pragma unroll
    for (int i = 0; i < 4; ++i) {
      float2 f0 = __half22float2(h0[i]);
      gg[2 * i + 0] = f0.x; gg[2 * i + 1] = f0.y;
      float2 f1 = __half22float2(h1[i]);
      gg[8 + 2 * i + 0] = f1.x; gg[8 + 2 * i + 1] = f1.y;
    }
  }

  float4 acc = make_float4(0.f, 0.f, 0.f, 0.f);
  float den = 0.f;

  const int j0 = off[n], j1 = off[n + 1];
  const int jlast = j1 - 1;
  const int hq = h * DK + q * 4;
  const int l8 = l & 7;
  const int se = l >> 2;   // staging edge 0..7
  const int sp = l & 3;    // staging float4-part

  if (j0 < j1) {
    // ---- prologue: pair(0) -> p, ea(0) -> er, pair(1) -> pn ----
    int2 p = pair[min(j0 + l8, jlast)];
    float4 er0, er1, er2, er3;
    {
      const int eid = __shfl(p.y, se, 32);
      const float4* s4 = (const float4*)(ea + (size_t)eid * ED) + sp;
      er0 = s4[0]; er1 = s4[4]; er2 = s4[8]; er3 = s4[12];
    }
    int2 pn = pair[min(j0 + 8 + l8, jlast)];

    for (int jp = j0; jp < j1; jp += 8) {
      // 1. ds_write ea(t)
      {
        float* d = &eas[g][se * ED] + sp * 4;
        *(float4*)(d + 0)  = er0; *(float4*)(d + 16) = er1;
        *(float4*)(d + 32) = er2; *(float4*)(d + 48) = er3;
      }
      // 2/3. prefetch ea(t+1) (addr from pn, already resident) + pair(t+2)
      int2 pf = pn;
      if (jp + 8 < j1) {
        const int eidN = __shfl(pn.y, se, 32);
        const float4* s4 = (const float4*)(ea + (size_t)eidN * ED) + sp;
        er0 = s4[0]; er1 = s4[4]; er2 = s4[8]; er3 = s4[12];
        pf = pair[min(jp + 16 + l8, jlast)];
      }
      // 4. staging visible to the 32-group
      asm volatile("s_waitcnt lgkmcnt(0)" ::: "memory");
      __builtin_amdgcn_sched_barrier(0);

      // 5. compute 8 edges
#pragma unroll
      for (int cb = 0; cb < 8; cb += 4) {
        const int col0 = __shfl(p.x, cb + 0, 32);
        const int col1 = __shfl(p.x, cb + 1, 32);
        const int col2 = __shfl(p.x, cb + 2, 32);
        const int col3 = __shfl(p.x, cb + 3, 32);

        LOADKV(col0, ka0, kb0, va0, vb0);
        LOADKV(col1, ka1, kb1, va1, vb1);
        LOADKV(col2, ka2, kb2, va2, vb2);
        LOADKV(col3, ka3, kb3, va3, vb3);

        float s0 = ka0.x * qv.x; s0 = fmaf(qv.y, ka0.y, s0); s0 = fmaf(qv.z, kb0.x, s0); s0 = fmaf(qv.w, kb0.y, s0);
        float s1 = ka1.x * qv.x; s1 = fmaf(qv.y, ka1.y, s1); s1 = fmaf(qv.z, kb1.x, s1); s1 = fmaf(qv.w, kb1.y, s1);
        float s2 = ka2.x * qv.x; s2 = fmaf(qv.y, ka2.y, s2); s2 = fmaf(qv.z, kb2.x, s2); s2 = fmaf(qv.w, kb2.y, s2);
        float s3 = ka3.x * qv.x; s3 = fmaf(qv.y, ka3.y, s3); s3 = fmaf(qv.z, kb3.x, s3); s3 = fmaf(qv.w, kb3.y, s3);

        const float4* e0 = (const float4*)&eas[g][(cb + 0) * ED + q * 16];
        const float4* e1 = (const float4*)&eas[g][(cb + 1) * ED + q * 16];
        const float4* e2 = (const float4*)&eas[g][(cb + 2) * ED + q * 16];
        const float4* e3 = (const float4*)&eas[g][(cb + 3) * ED + q * 16];
#pragma unroll
        for (int i = 0; i < 4; ++i) {
          float4 a = e0[i];
          s0 = fmaf(a.x, gg[4 * i + 0], s0); s0 = fmaf(a.y, gg[4 * i + 1], s0);
          s0 = fmaf(a.z, gg[4 * i + 2], s0); s0 = fmaf(a.w, gg[4 * i + 3], s0);
        }
#pragma unroll
        for (int i = 0; i < 4; ++i) {
          float4 a = e1[i];
          s1 = fmaf(a.x, gg[4 * i + 0], s1); s1 = fmaf(a.y, gg[4 * i + 1], s1);
          s1 = fmaf(a.z, gg[4 * i + 2], s1); s1 = fmaf(a.w, gg[4 * i + 3], s1);
        }
#pragma unroll
        for (int i = 0; i < 4; ++i) {
          float4 a = e2[i];
          s2 = fmaf(a.x, gg[4 * i + 0], s2); s2 = fmaf(a.y, gg[4 * i + 1], s2);
          s2 = fmaf(a.z, gg[4 * i + 2], s2); s2 = fmaf(a.w, gg[4 * i + 3], s2);
        }
#pragma unroll
        for (int i = 0; i < 4; ++i) {
          float4 a = e3[i];
          s3 = fmaf(a.x, gg[4 * i + 0], s3); s3 = fmaf(a.y, gg[4 * i + 1], s3);
          s3 = fmaf(a.z, gg[4 * i + 2], s3); s3 = fmaf(a.w, gg[4 * i + 3], s3);
        }

        s0 += __shfl_xor(s0, 1); s0 += __shfl_xor(s0, 2);
        s1 += __shfl_xor(s1, 1); s1 += __shfl_xor(s1, 2);
        s2 += __shfl_xor(s2, 1); s2 += __shfl_xor(s2, 2);
        s3 += __shfl_xor(s3, 1); s3 += __shfl_xor(s3, 2);

        const float es0 = (jp + cb + 0 < j1) ? __expf(s0 + sb) : 0.f;
        const float es1 = (jp + cb + 1 < j1) ? __expf(s1 + sb) : 0.f;
        const float es2 = (jp + cb + 2 < j1) ? __expf(s2 + sb) : 0.f;
        const float es3 = (jp + cb + 3 < j1) ? __expf(s3 + sb) : 0.f;
        den += (es0 + es1) + (es2 + es3);

        acc.x = fmaf(es0, va0.x, acc.x); acc.y = fmaf(es0, va0.y, acc.y);
        acc.z = fmaf(es0, vb0.x, acc.z); acc.w = fmaf(es0, vb0.y, acc.w);
        acc.x = fmaf(es1, va1.x, acc.x); acc.y = fmaf(es1, va1.y, acc.y);
        acc.z = fmaf(es1, vb1.x, acc.z); acc.w = fmaf(es1, vb1.y, acc.w);
        acc.x = fmaf(es2, va2.x, acc.x); acc.y = fmaf(es2, va2.y, acc.y);
        acc.z = fmaf(es2, vb2.x, acc.z); acc.w = fmaf(es2, vb2.y, acc.w);
        acc.x = fmaf(es3, va3.x, acc.x); acc.y = fmaf(es3, va3.y, acc.y);
        acc.z = fmaf(es3, vb3.x, acc.z); acc.w = fmaf(es3, vb3.y, acc.w);
      }

      p = pn; pn = pf;
    }
  }

  const float inv = 1.f / (den + 1e-8f);
  float4 o;
  o.x = acc.x * inv; o.y = acc.y * inv; o.z = acc.z * inv; o.w = acc.w * inv;
  *(float4*)(msgn + (size_t)n * ND + h * DK + q * 4) = o;
}

extern "C" void kernel_launch(void* const* d_in, const int* in_sizes, int n_in,
                              void* d_out, int out_size, void* d_ws, size_t ws_size,
                              hipStream_t stream) {
  const float* nodes = (const float*)d_in[0];
  const int*   ei    = (const int*)d_in[1];
  const float* ea    = (const float*)d_in[2];
  const float* wq    = (const float*)d_in[3];
  const float* bq    = (const float*)d_in[4];
  const float* wk    = (const float*)d_in[5];
  const float* bk    = (const float*)d_in[6];
  const float* wv    = (const float*)d_in[7];
  const float* bv    = (const float*)d_in[8];
  const float* we    = (const float*)d_in[9];
  const float* be    = (const float*)d_in[10];
  const float* wo    = (const float*)d_in[11];
  const float* bo    = (const float*)d_in[12];
  float* out = (float*)d_out;

  float* ws = (float*)d_ws;
  const size_t NND = (size_t)NN * ND;
  float*  Q    = ws;                         // NND f32
  float*  msgn = Q + NND;                    // NND f32
  __half* K16  = (__half*)(msgn + NND);      // NND f16
  __half* V16  = K16 + NND;                  // NND f16
  int* hist    = (int*)(V16 + NND);          // NN
  int* off     = hist + NN;                  // 40004
  int* cursor  = off + 40004;                // NN
  int* bsum    = cursor + NN;                // 256
  int2* pair   = (int2*)(bsum + 256);        // NE
  float* SB    = (float*)(pair + NE);        // NN*NH f32
  __half2* G16 = (__half2*)(SB + (size_t)NN * NH);  // NN*512 f16

  hipMemsetAsync(hist, 0, NN * sizeof(int), stream);

  dim3 blk(256);

  proj_qkv_g<<<dim3(NN / 16), blk, 0, stream>>>(nodes, wq, bq, wk, bk, wv, bv,
                                                we, be, Q, K16, V16, G16, SB);

  dim3 gE((NE + 255) / 256);
  k_hist<<<gE, blk, 0, stream>>>(ei, hist);
  k_scan1<<<dim3(SCAN_NBLK), blk, 0, stream>>>(hist, off, bsum);
  k_scan2<<<dim3(1), blk, 0, stream>>>(bsum);
  k_scan3<<<dim3(SCAN_NBLK), blk, 0, stream>>>(off, bsum, cursor);
  k_scatter<<<gE, blk, 0, stream>>>(ei, cursor, pair);

  k_gather<<<dim3(NN / 8), blk, 0, stream>>>(Q, K16, V16, ea, off, pair, G16, SB, msgn);

  proj128<<<dim3(NN / 16), blk, 0, stream>>>(msgn, wo, bo, out);
}